// Round 18
// baseline (252.380 us; speedup 1.0000x reference)
//
#include <hip/hip_runtime.h>

#define N_ANCH 8732
#define NCLS   21
#define BATCH  128
#define TOPK   200
#define KPT    35          // ceil(8732/256)
#define CONF_T 0.01f
#define NMS_T  0.45f

// XLA:CPU GenerateVF32Exp (classic Cephes) compiled with AllowFPOpFusion=Fast:
//   fx = floor(fma(x, log2e, 0.5))
//   t  = fma(fx, -0.693359375, x); t = fma(fx, 2.12194440e-4, t)
//   FMA-Horner p0..p5; y = fma(y, t*t, t); y += 1;  result = y * 2^fx (exact)
__device__ __forceinline__ float exp_np(float x) {
    const float fx = floorf(__fmaf_rn(x, 1.442695040888963f, 0.5f));
    float t = __fmaf_rn(fx, -0.693359375f, x);
    t = __fmaf_rn(fx, 2.12194440e-4f, t);
    const float z = __fmul_rn(t, t);
    float y = 1.9875691500e-4f;
    y = __fmaf_rn(y, t, 1.3981999507e-3f);
    y = __fmaf_rn(y, t, 8.3334519073e-3f);
    y = __fmaf_rn(y, t, 4.1665795894e-2f);
    y = __fmaf_rn(y, t, 1.6666665459e-1f);
    y = __fmaf_rn(y, t, 5.0000001201e-1f);
    y = __fmaf_rn(y, z, t);
    y = __fadd_rn(y, 1.0f);
    return ldexpf(y, (int)fx);
}

// ---------------------------------------------------------------------------
// Kernel A: softmax with VF=16 masked-tail vectorized reduce:
//   acc[j] = e[j] + e[16+j]  (j<5, masked 2nd iter)   acc[j] = e[j]  (5<=j<16)
//   u[j] = acc[j] + acc[j+8]  (16->8)   [= (e[j]+e[16+j]) + e[j+8] for j<5]
//   v[j] = u[j] + u[j+4]; w[j] = v[j] + v[j+2]; s = w0 + w1
// Decode with ISel FMA fusion: cx = fma(l*0.1, dz, dx); x1 = fma(w,-0.5,cx).
// probs transposed [b][c-1][n]; boxes [b][n][4].
// ---------------------------------------------------------------------------
__global__ __launch_bounds__(256) void prep_kernel(
    const float* __restrict__ loc, const float* __restrict__ conf,
    const float* __restrict__ dbox, float* __restrict__ probs,
    float* __restrict__ boxes)
{
    __shared__ float srow[256 * NCLS];
    const int block_row0 = blockIdx.x * 256;
    const float* cbase = conf + (size_t)block_row0 * NCLS;
    for (int i = threadIdx.x; i < 256 * NCLS; i += 256) srow[i] = cbase[i];
    __syncthreads();

    const int row = block_row0 + threadIdx.x;      // grid exact: 4366*256
    const int b = row / N_ANCH;
    const int n = row - b * N_ANCH;

    float e[NCLS];
    float m = srow[threadIdx.x * NCLS];
#pragma unroll
    for (int c = 1; c < NCLS; ++c) m = fmaxf(m, srow[threadIdx.x * NCLS + c]);
#pragma unroll
    for (int c = 0; c < NCLS; ++c)
        e[c] = exp_np(__fsub_rn(srow[threadIdx.x * NCLS + c], m));

    // VF=16 masked-tail reduce
    float acc[16];
#pragma unroll
    for (int j = 0; j < 16; ++j) acc[j] = e[j];
#pragma unroll
    for (int j = 0; j < 5; ++j) acc[j] = __fadd_rn(acc[j], e[16 + j]);
    float u[8];
#pragma unroll
    for (int j = 0; j < 8; ++j) u[j] = __fadd_rn(acc[j], acc[j + 8]);
    const float v0 = __fadd_rn(u[0], u[4]), v1 = __fadd_rn(u[1], u[5]);
    const float v2 = __fadd_rn(u[2], u[6]), v3 = __fadd_rn(u[3], u[7]);
    const float w0 = __fadd_rn(v0, v2), w1 = __fadd_rn(v1, v3);
    const float s  = __fadd_rn(w0, w1);

#pragma unroll
    for (int c = 1; c < NCLS; ++c)
        probs[((size_t)b * 20 + (c - 1)) * N_ANCH + n] = __fdiv_rn(e[c], s);

    const float4 l = *(const float4*)(loc + (size_t)row * 4);
    const float4 d = *(const float4*)(dbox + (size_t)n * 4);
    const float cx = __fmaf_rn(__fmul_rn(l.x, 0.1f), d.z, d.x);
    const float cy = __fmaf_rn(__fmul_rn(l.y, 0.1f), d.w, d.y);
    const float w  = __fmul_rn(d.z, exp_np(__fmul_rn(l.z, 0.2f)));
    const float h  = __fmul_rn(d.w, exp_np(__fmul_rn(l.w, 0.2f)));
    const float x1 = __fmaf_rn(w, -0.5f, cx);
    const float y1 = __fmaf_rn(h, -0.5f, cy);
    float4 o; o.x = x1; o.y = y1; o.z = __fadd_rn(x1, w); o.w = __fadd_rn(y1, h);
    *(float4*)(boxes + (size_t)row * 4) = o;
}

// ---------------------------------------------------------------------------
// Kernel B: one block per (b,c). Exact top-200 on f32 bit keys (value desc,
// index ASC among equals = lax.top_k), f32 NMS exact op order.
// ---------------------------------------------------------------------------
__global__ __launch_bounds__(256) void nms_kernel(
    const float* __restrict__ probs, const float* __restrict__ boxes,
    float* __restrict__ out)
{
    const int task = blockIdx.x;                  // b*21 + c
    const int b = task / NCLS;
    const int c = task - b * NCLS;
    float* obase = out + (size_t)task * (TOPK * 5);
    const int tid = threadIdx.x;

    if (c == 0) {
        for (int i = tid; i < TOPK * 5; i += 256) obase[i] = 0.f;
        return;
    }
    const float* prow = probs + ((size_t)b * 20 + (c - 1)) * N_ANCH;

    unsigned key[KPT];
#pragma unroll
    for (int k = 0; k < KPT; ++k) {
        const int n = k * 256 + tid;
        const float s = (n < N_ANCH) ? prow[n] : -1.f;
        key[k] = (s > CONF_T) ? __float_as_uint(s) : 0u;   // positive f32: bit order = value order
    }

    __shared__ int red_i[4];
    __shared__ unsigned ck[TOPK];
    __shared__ int  cn[TOPK];
    __shared__ int  tie_n[128];
    __shared__ int  cnts[2];
    __shared__ unsigned sk[TOPK];
    __shared__ int  sn_[TOPK];
    __shared__ float bx1[TOPK], by1[TOPK], bx2[TOPK], by2[TOPK], bar[TOPK], bsc[TOPK];
    __shared__ int  keep[TOPK], pos_[TOPK];
    __shared__ float outrow[TOPK * 5];

    // ---- binary search: T = max threshold with count(>=T) >= 200 ---------
    unsigned T = 0u;
    for (int bit = 30; bit >= 0; --bit) {
        const unsigned cand = T | (1u << bit);
        int cnt = 0;
#pragma unroll
        for (int k = 0; k < KPT; ++k) cnt += (key[k] >= cand) ? 1 : 0;
        for (int off = 32; off; off >>= 1) cnt += __shfl_xor(cnt, off);
        if ((tid & 63) == 0) red_i[tid >> 6] = cnt;
        __syncthreads();
        const int total = red_i[0] + red_i[1] + red_i[2] + red_i[3];
        if (total >= TOPK) T = cand;
        __syncthreads();
    }

    // ---- compact: keys > T (<=199); ties at T by LOWEST index -------------
    if (tid == 0) { cnts[0] = 0; cnts[1] = 0; }
    __syncthreads();
#pragma unroll
    for (int k = 0; k < KPT; ++k) {
        const unsigned kk = key[k];
        if (kk > T) {
            const int p = atomicAdd(&cnts[0], 1);
            ck[p] = kk; cn[p] = k * 256 + tid;
        } else if (T != 0u && kk == T) {
            const int p = atomicAdd(&cnts[1], 1);
            if (p < 128) tie_n[p] = k * 256 + tid;
        }
    }
    __syncthreads();
    if (tid == 0 && T != 0u) {
        const int base = cnts[0];
        int slots = TOPK - base;
        int tc = cnts[1] > 128 ? 128 : cnts[1];
        if (slots > tc) slots = tc;
        for (int i = 1; i < tc; ++i) {            // insertion sort ASC index
            const int x = tie_n[i]; int j = i - 1;
            while (j >= 0 && tie_n[j] > x) { tie_n[j + 1] = tie_n[j]; --j; }
            tie_n[j + 1] = x;
        }
        for (int i = 0; i < slots; ++i) { ck[base + i] = T; cn[base + i] = tie_n[i]; }
        cnts[0] = base + slots;
    }
    __syncthreads();
    const int cnt_arr = cnts[0];                  // <= 200

    // ---- rank-sort: (value desc, index ASC among equals) ------------------
    if (tid < TOPK) { sk[tid] = 0u; sn_[tid] = -1; }
    __syncthreads();
    if (tid < cnt_arr) {
        const unsigned mk = ck[tid];
        const int mn = cn[tid];
        int rank = 0;
        for (int j = 0; j < cnt_arr; ++j) {
            const unsigned kj = ck[j];
            rank += (kj > mk || (kj == mk && cn[j] < mn)) ? 1 : 0;
        }
        sk[rank] = mk; sn_[rank] = mn;
    }
    __syncthreads();

    // ---- gather boxes (f32), init keep ------------------------------------
    if (tid < TOPK) {
        const int n = sn_[tid];
        float sc = 0.f;
        float4 bx = make_float4(0.f, 0.f, 0.f, 0.f);
        if (n >= 0) {
            sc = __uint_as_float(sk[tid]);
            bx = *(const float4*)(boxes + ((size_t)b * N_ANCH + n) * 4);
        }
        bsc[tid] = sc;
        bx1[tid] = bx.x; by1[tid] = bx.y; bx2[tid] = bx.z; by2[tid] = bx.w;
        bar[tid] = __fmul_rn(__fsub_rn(bx.z, bx.x), __fsub_rn(bx.w, bx.y));
        keep[tid] = (sc > CONF_T) ? 1 : 0;
    }
    __syncthreads();

    // ---- sequential NMS, exact f32 op order -------------------------------
    for (int i = 0; i < TOPK; ++i) {
        if (tid > i && tid < TOPK && keep[i] && keep[tid]) {
            const float w = fmaxf(0.f, __fsub_rn(fminf(bx2[tid], bx2[i]), fmaxf(bx1[tid], bx1[i])));
            const float h = fmaxf(0.f, __fsub_rn(fminf(by2[tid], by2[i]), fmaxf(by1[tid], by1[i])));
            const float inter = __fmul_rn(w, h);
            const float denom = __fadd_rn(__fsub_rn(bar[tid], inter), bar[i]);
            const float iou = __fdiv_rn(inter, denom);
            if (iou > NMS_T) keep[tid] = 0;
        }
        __syncthreads();
    }

    // ---- stable compaction + zero fill ------------------------------------
    if (tid == 0) {
        int cc = 0;
        for (int rr = 0; rr < TOPK; ++rr) { pos_[rr] = cc; cc += keep[rr]; }
    }
    __syncthreads();
    for (int i = tid; i < TOPK * 5; i += 256) outrow[i] = 0.f;
    __syncthreads();
    if (tid < TOPK && keep[tid]) {
        const int d = pos_[tid];
        outrow[d * 5 + 0] = bsc[tid];
        outrow[d * 5 + 1] = bx1[tid];
        outrow[d * 5 + 2] = by1[tid];
        outrow[d * 5 + 3] = bx2[tid];
        outrow[d * 5 + 4] = by2[tid];
    }
    __syncthreads();
    for (int i = tid; i < TOPK * 5; i += 256) obase[i] = outrow[i];
}

extern "C" void kernel_launch(void* const* d_in, const int* in_sizes, int n_in,
                              void* d_out, int out_size, void* d_ws, size_t ws_size,
                              hipStream_t stream) {
    (void)in_sizes; (void)n_in; (void)out_size; (void)ws_size;
    const float* loc  = (const float*)d_in[0];
    const float* conf = (const float*)d_in[1];
    const float* dbox = (const float*)d_in[2];
    float* out   = (float*)d_out;
    float* probs = (float*)d_ws;                                            // 89,415,680 B
    float* boxes = (float*)((char*)d_ws + (size_t)BATCH * 20 * N_ANCH * 4); // +17,883,136 B

    prep_kernel<<<(BATCH * N_ANCH) / 256, 256, 0, stream>>>(loc, conf, dbox, probs, boxes);
    nms_kernel<<<BATCH * NCLS, 256, 0, stream>>>(probs, boxes, out);
}